// Round 15
// baseline (130.453 us; speedup 1.0000x reference)
//
#include <hip/hip_runtime.h>
#include <stdint.h>

typedef __attribute__((ext_vector_type(8))) short short8;
typedef __attribute__((ext_vector_type(4))) float f32x4;

#define AS1(p) ((const __attribute__((address_space(1))) void*)(p))
#define AS3(p) ((__attribute__((address_space(3))) void*)(p))

__device__ __forceinline__ void gload_lds16(const void* g, void* l) {
  __builtin_amdgcn_global_load_lds(AS1(g), AS3(l), 16, 0, 0);
}

__device__ __forceinline__ uint32_t cvtpk_bf16(float a, float b) {
  uint32_t d;
  asm("v_cvt_pk_bf16_f32 %0, %1, %2" : "=v"(d) : "v"(a), "v"(b));
  return d;
}

__device__ __forceinline__ float fast_exp2(float x) {
#if __has_builtin(__builtin_amdgcn_exp2f)
  return __builtin_amdgcn_exp2f(x);
#else
  return exp2f(x);
#endif
}

// Q pre-scale: 1/sqrt(64) * log2(e)  (exp2-based softmax)
#define QSCALE 0.1803368801111244f

// ---------------- fused prep: x/wqkv/wo casts + bias concat (one launch) ----------------
__global__ void prep_k(const float* __restrict__ x, const float* __restrict__ wq,
                       const float* __restrict__ wk, const float* __restrict__ wv,
                       const float* __restrict__ wo, const float* __restrict__ bq,
                       const float* __restrict__ bk, const float* __restrict__ bv,
                       uint2* __restrict__ xb, uint2* __restrict__ wqkvb,
                       uint2* __restrict__ mob, float* __restrict__ bqkv) {
  const int bid = blockIdx.x, tid = threadIdx.x;
  if (bid < 4096) {                       // cast x -> bf16
    int i = bid * 256 + tid;
    float4 v = ((const float4*)x)[i];
    uint2 o; o.x = cvtpk_bf16(v.x, v.y); o.y = cvtpk_bf16(v.z, v.w);
    xb[i] = o;
  } else if (bid < 7168) {                // concat+cast W_Q|W_K|W_V (already [n][k])
    int i = (bid - 4096) * 256 + tid;
    int e = i * 4;
    const float* src = (e < (1 << 20)) ? (wq + e)
                     : (e < (2 << 20)) ? (wk + (e - (1 << 20)))
                                       : (wv + (e - (2 << 20)));
    float4 v = *(const float4*)src;
    uint2 o; o.x = cvtpk_bf16(v.x, v.y); o.y = cvtpk_bf16(v.z, v.w);
    wqkvb[i] = o;
  } else if (bid < 8192) {                // gather+cast W_O -> [d][i*64+h]
    int i = (bid - 7168) * 256 + tid;
    int o4 = i * 4;
    int d = o4 >> 10, c = o4 & 1023;
    const float* s = wo + ((c >> 6) << 16) + (d << 6) + (c & 63);
    float4 v = *(const float4*)s;
    uint2 o; o.x = cvtpk_bf16(v.x, v.y); o.y = cvtpk_bf16(v.z, v.w);
    mob[i] = o;
  } else {                                // bias concat (fp32)
    int i = (bid - 8192) * 256 + tid;
    bqkv[i] = (i < 1024) ? bq[i] : (i < 2048) ? bk[i - 1024] : bv[i - 2048];
  }
}

// ---------------- GEMM: C[M,N] = A[M,K] * B^T (B stored [N][K]) + bias ----------------
// BK=64 + T2 XOR-swizzle (R10-proven).
template <int EPI>
__global__ __launch_bounds__(256) void gemm_bt(const short* __restrict__ A,
                                               const short* __restrict__ Bm,
                                               const float* __restrict__ bias,
                                               void* __restrict__ Cout, int K, int ldc) {
  __shared__ short As[128 * 64];
  __shared__ short Bs[128 * 64];
  const int t = threadIdx.x;
  const int l = t & 63, w = t >> 6;
  const int wr = w >> 1, wc = w & 1;
  const int q = l & 15, g = l >> 4;
  const long brow = (long)blockIdx.y * 128;
  const long bcol = (long)blockIdx.x * 128;
  f32x4 acc[4][4] = {};
  const int r8 = t >> 3;
  const int sc8 = (t & 7) ^ (r8 & 7);
  const short* aptr = A + (brow + r8) * (long)K + sc8 * 8;
  const short* bptr = Bm + (bcol + r8) * (long)K + sc8 * 8;
  const int qs = q & 7;
  for (int k0 = 0; k0 < K; k0 += 64) {
#pragma unroll
    for (int c = 0; c < 4; ++c) {
      gload_lds16(aptr + k0 + c * 32 * (long)K, &As[(c * 256 + t) * 8]);
      gload_lds16(bptr + k0 + c * 32 * (long)K, &Bs[(c * 256 + t) * 8]);
    }
    __syncthreads();
    short8 af[4][2], bfr[4][2];
#pragma unroll
    for (int m = 0; m < 4; ++m)
#pragma unroll
      for (int kk = 0; kk < 2; ++kk)
        af[m][kk] = *(const short8*)&As[(wr * 64 + m * 16 + q) * 64 + ((kk * 4 + g) ^ qs) * 8];
#pragma unroll
    for (int n = 0; n < 4; ++n)
#pragma unroll
      for (int kk = 0; kk < 2; ++kk)
        bfr[n][kk] = *(const short8*)&Bs[(wc * 64 + n * 16 + q) * 64 + ((kk * 4 + g) ^ qs) * 8];
#pragma unroll
    for (int m = 0; m < 4; ++m)
#pragma unroll
      for (int n = 0; n < 4; ++n) {
        acc[m][n] = __builtin_amdgcn_mfma_f32_16x16x32_bf16(af[m][0], bfr[n][0], acc[m][n], 0, 0, 0);
        acc[m][n] = __builtin_amdgcn_mfma_f32_16x16x32_bf16(af[m][1], bfr[n][1], acc[m][n], 0, 0, 0);
      }
    if (k0 + 64 < K) __syncthreads();
  }
#pragma unroll
  for (int m = 0; m < 4; ++m)
#pragma unroll
    for (int n = 0; n < 4; ++n)
#pragma unroll
      for (int r = 0; r < 4; ++r) {
        long row = brow + wr * 64 + m * 16 + g * 4 + r;
        long col = bcol + wc * 64 + n * 16 + q;
        float v = acc[m][n][r] + bias[col];
        if (EPI == 0) {
          if (col < 1024) v *= QSCALE;
          ((unsigned short*)Cout)[row * ldc + col] = (unsigned short)cvtpk_bf16(v, v);
        } else {
          ((float*)Cout)[row * ldc + col] = v;
        }
      }
}

// ---------------- flash attention (subset-paired q-tiles, 128-key KV steps) ----------------
// R12 structure with KV tile = 128 keys = 2 proven 64-wide halves. Per block:
// nTA = ceil((qtA+1)/2) iterations (avg 12.75, was 24.5) — barriers, drains,
// shfl-reduces per key HALVED. Blocks c,c+256 share a CU; iteration sum = 25
// constant. All sub-patterns (staging, swizzles, fragments) R12-verbatim.
__global__ __launch_bounds__(256) void attn(const short* __restrict__ qkv,
                                            unsigned short* __restrict__ zb) {
  __shared__ short Ks[2][2 * 64 * 64];           // [buf][half*4096]
  __shared__ short Vt[2 * 64 * 64];              // [half*4096]
  __shared__ unsigned short Ps[8][2 * 16 * 64];  // [region][half*1024]
  const int bid = blockIdx.x;
  const int r_ = bid >> 7;                 // 0..3
  const int u_ = (bid >> 3) & 15;          // 0..15
  const int x_ = bid & 7;                  // XCD slot (4 heads per slot -> L2 reuse)
  const int bh = r_ * 8 + x_;              // head 0..31
  const int pr = (r_ < 2) ? u_ : 15 - u_;  // work-balancing: pr(c)+pr(c+256)=15
  const int qtA = 31 - pr, qtB = pr;
  const int nTA = (33 - pr) >> 1;          // ceil((qtA+1)/2)
  const int nTB = (qtB + 2) >> 1;          // ceil((qtB+1)/2)
  const int b = bh >> 4, h = bh & 15;
  const int t = threadIdx.x, l = t & 63, w = t >> 6;
  const int lq = l & 15, g = l >> 4;
  const int u = t >> 3, c8 = t & 7;        // staging coords
  const long rowbase = (long)b * 2048;
  const short* qp = qkv + rowbase * 3072 + h * 64;
  const short* kp = qp + 1024;
  const short* vp = qp + 2048;

  short8 qfA[2], qfB[2];
#pragma unroll
  for (int kg = 0; kg < 2; ++kg) {
    qfA[kg] = *(const short8*)(qp + (long)(qtA * 64 + w * 16 + lq) * 3072 + kg * 32 + g * 8);
    qfB[kg] = *(const short8*)(qp + (long)(qtB * 64 + w * 16 + lq) * 3072 + kg * 32 + g * 8);
  }
  f32x4 zA[4] = {}, zB[4] = {};
  float mA = -1e30f, lA = 0.0f, mB = -1e30f, lB = 0.0f;

  // one attention step over a staged 128-key tile (two proven 64-wide halves)
  auto step = [&](const short* ksb, unsigned short* Pw, f32x4 (&zacc)[4],
                  float& mrun, float& lrun, short8 (&qf)[2], bool diag, int dOff) {
    f32x4 sacc[8];
#pragma unroll
    for (int m = 0; m < 8; ++m) {
      sacc[m] = f32x4{0.f, 0.f, 0.f, 0.f};
      int half = m >> 2, mh = m & 3;
      int krow = mh * 16 + lq;
#pragma unroll
      for (int kg = 0; kg < 2; ++kg) {
        int blk = kg * 4 + g;
        short8 kf = *(const short8*)&ksb[half * 4096 + krow * 64 + (blk ^ (krow & 7)) * 8];
        sacc[m] = __builtin_amdgcn_mfma_f32_16x16x32_bf16(kf, qf[kg], sacc[m], 0, 0, 0);
      }
    }
    if (diag) {
#pragma unroll
      for (int m = 0; m < 8; ++m) {
        int half = m >> 2, mh = m & 3;
#pragma unroll
        for (int r = 0; r < 4; ++r)
          if (half * 64 + mh * 16 + g * 4 + r > dOff + w * 16 + lq) sacc[m][r] = -1e30f;
      }
    }
    // tree max (depth 5, 32 values)
    float red[16];
#pragma unroll
    for (int i2 = 0; i2 < 16; ++i2)
      red[i2] = fmaxf(sacc[i2 >> 2][i2 & 3], sacc[4 + (i2 >> 2)][i2 & 3]);
#pragma unroll
    for (int i2 = 0; i2 < 8; ++i2) red[i2] = fmaxf(red[i2], red[i2 + 8]);
#pragma unroll
    for (int i2 = 0; i2 < 4; ++i2) red[i2] = fmaxf(red[i2], red[i2 + 4]);
    float mx = fmaxf(fmaxf(red[0], red[2]), fmaxf(red[1], red[3]));
    mx = fmaxf(mx, __shfl_xor(mx, 16));
    mx = fmaxf(mx, __shfl_xor(mx, 32));
    // defer-max: rescale only when tile max overflows the 2^8 headroom
    if (!__all(mx <= mrun + 8.0f)) {
      float mnew = fmaxf(mrun, mx);
      float alpha = fast_exp2(mrun - mnew);
      lrun *= alpha;
#pragma unroll
      for (int r = 0; r < 4; ++r) {
        float ar = __shfl(alpha, g * 4 + r);
#pragma unroll
        for (int n2 = 0; n2 < 4; ++n2) zacc[n2][r] *= ar;
      }
      mrun = mnew;
    }
#pragma unroll
    for (int m = 0; m < 8; ++m)
#pragma unroll
      for (int r = 0; r < 4; ++r) sacc[m][r] = fast_exp2(sacc[m][r] - mrun);
    // tree sum (depth 5)
    float rs[16];
#pragma unroll
    for (int i2 = 0; i2 < 16; ++i2)
      rs[i2] = sacc[i2 >> 2][i2 & 3] + sacc[4 + (i2 >> 2)][i2 & 3];
#pragma unroll
    for (int i2 = 0; i2 < 8; ++i2) rs[i2] = rs[i2] + rs[i2 + 8];
#pragma unroll
    for (int i2 = 0; i2 < 4; ++i2) rs[i2] = rs[i2] + rs[i2 + 4];
    float ts = (rs[0] + rs[2]) + (rs[1] + rs[3]);
    ts += __shfl_xor(ts, 16);
    ts += __shfl_xor(ts, 32);
    lrun += ts;
    // pack P (cvt_pk) -> per-half LDS sub-regions (proven swizzle per half)
#pragma unroll
    for (int m = 0; m < 8; ++m) {
      int half = m >> 2, mh = m & 3;
      uint2 wv;
      wv.x = cvtpk_bf16(sacc[m][0], sacc[m][1]);
      wv.y = cvtpk_bf16(sacc[m][2], sacc[m][3]);
      int c = mh * 4 + g;
      int csw = c ^ ((lq & 7) << 1);
      *(uint2*)&Pw[half * 1024 + lq * 64 + csw * 4] = wv;
    }
    short8 pf[4];
#pragma unroll
    for (int kg2 = 0; kg2 < 4; ++kg2) {
      int half = kg2 >> 1, k2 = kg2 & 1;
      int c0 = k2 * 8 + g * 2;
      int c0s = c0 ^ ((lq & 7) << 1);
      pf[kg2] = *(const short8*)&Pw[half * 1024 + lq * 64 + c0s * 4];
    }
#pragma unroll
    for (int n2 = 0; n2 < 4; ++n2) {
#pragma unroll
      for (int kg2 = 0; kg2 < 4; ++kg2) {
        int half = kg2 >> 1;
        int dh = n2 * 16 + lq;
        int sw = (dh & 7) ^ ((dh >> 3) & 7);
        int blk = (kg2 & 1) * 4 + g;
        short8 vf = *(const short8*)&Vt[half * 4096 + dh * 64 + ((blk ^ sw) * 8)];
        zacc[n2] = __builtin_amdgcn_mfma_f32_16x16x32_bf16(pf[kg2], vf, zacc[n2], 0, 0, 0);
      }
    }
  };

  short8 va0, va1, va2, va3;   // V rows: half0 {2u,2u+1}, half1 {64+2u,64+2u+1}
  auto stageKK = [&](int tile, int buf) {
#pragma unroll
    for (int hf = 0; hf < 2; ++hf)
#pragma unroll
      for (int i = 0; i < 2; ++i) {
        int r = i * 32 + u;
        int cbk = (c8 ^ (r & 7)) * 8;
        gload_lds16(kp + ((long)tile * 128 + hf * 64 + r) * 3072 + cbk,
                    &Ks[buf][hf * 4096 + i * 2048 + t * 8]);
      }
  };
  auto loadV = [&](int tile) {
    const short* vrow = vp + ((long)tile * 128 + 2 * u) * 3072 + c8 * 8;
    va0 = *(const short8*)vrow;
    va1 = *(const short8*)(vrow + 3072);
    va2 = *(const short8*)(vrow + 64 * 3072);
    va3 = *(const short8*)(vrow + 65 * 3072);
  };
  auto writeVt = [&]() {
    int blk = u >> 2, rl = (u & 3) * 2;
#pragma unroll
    for (int idx = 0; idx < 8; ++idx) {
      int dh = c8 * 8 + idx;
      int sw = (dh & 7) ^ ((dh >> 3) & 7);
      uint32_t p0 = (uint32_t)(uint16_t)va0[idx] | ((uint32_t)(uint16_t)va1[idx] << 16);
      uint32_t p1 = (uint32_t)(uint16_t)va2[idx] | ((uint32_t)(uint16_t)va3[idx] << 16);
      *(uint32_t*)&Vt[dh * 64 + ((blk ^ sw) * 8) + rl] = p0;
      *(uint32_t*)&Vt[4096 + dh * 64 + ((blk ^ sw) * 8) + rl] = p1;
    }
  };

  // prologue: issue staging for kv tile 0 into buffer 0
  stageKK(0, 0);
  loadV(0);

  for (int jj = 0; jj < nTA; ++jj) {
    const int buf = jj & 1;
    asm volatile("s_waitcnt vmcnt(0)" ::: "memory");
    __builtin_amdgcn_sched_barrier(0);
    __builtin_amdgcn_s_barrier();   // K(jj) in LDS; prev step's Vt/Ks readers done
    writeVt();                      // V regs -> Vt (prev readers done pre-barrier)
    if (jj + 1 < nTA) {
      stageKK(jj + 1, buf ^ 1);     // prefetch next 128-key tile under compute
      loadV(jj + 1);
    }
    asm volatile("s_waitcnt lgkmcnt(0)" ::: "memory");  // Vt writes visible
    __builtin_amdgcn_sched_barrier(0);
    __builtin_amdgcn_s_barrier();
    step(&Ks[buf][0], &Ps[w][0], zA, mA, lA, qfA, jj == nTA - 1, qtA * 64 - jj * 128);
    if (jj < nTB)
      step(&Ks[buf][0], &Ps[4 + w][0], zB, mB, lB, qfB, jj == nTB - 1, qtB * 64 - jj * 128);
  }

  auto wout = [&](f32x4 (&zacc)[4], float lrun, int qt) {
#pragma unroll
    for (int r = 0; r < 4; ++r) {
      float linv = 1.0f / __shfl(lrun, g * 4 + r);
      long grow = rowbase + qt * 64 + w * 16 + g * 4 + r;
#pragma unroll
      for (int n2 = 0; n2 < 4; ++n2) {
        int col = h * 64 + n2 * 16 + lq;
        float zv = zacc[n2][r] * linv;
        zb[grow * 1024 + col] = (unsigned short)cvtpk_bf16(zv, zv);
      }
    }
  };
  wout(zA, lA, qtA);
  wout(zB, lB, qtB);
}

extern "C" void kernel_launch(void* const* d_in, const int* in_sizes, int n_in,
                              void* d_out, int out_size, void* d_ws, size_t ws_size,
                              hipStream_t stream) {
  const float* x  = (const float*)d_in[0];
  const float* wq = (const float*)d_in[1];
  const float* wk = (const float*)d_in[2];
  const float* wv = (const float*)d_in[3];
  const float* wo = (const float*)d_in[4];
  const float* bq = (const float*)d_in[5];
  const float* bk = (const float*)d_in[6];
  const float* bv = (const float*)d_in[7];
  const float* bo = (const float*)d_in[8];
  char* ws = (char*)d_ws;
  if (ws_size < ((size_t)48 * 1024 * 1024 + 16384)) return;  // need ~48MB
  short*          xb    = (short*)(ws);                         //  8 MB
  short*          qkvb  = (short*)(ws + ((size_t)8  << 20));    // 24 MB
  unsigned short* zbuf  = (unsigned short*)(ws + ((size_t)32 << 20)); // 8 MB
  short*          wqkvb = (short*)(ws + ((size_t)40 << 20));    //  6 MB
  short*          mob   = (short*)(ws + ((size_t)46 << 20));    //  2 MB
  float*          bqkv  = (float*)(ws + ((size_t)48 << 20));    // 12 KB

  prep_k<<<8204, 256, 0, stream>>>(x, wq, wk, wv, wo, bq, bk, bv,
                                   (uint2*)xb, (uint2*)wqkvb, (uint2*)mob, bqkv);
  gemm_bt<0><<<dim3(24, 32), 256, 0, stream>>>(xb, wqkvb, bqkv, (void*)qkvb, 1024, 3072);
  attn      <<<512,          256, 0, stream>>>(qkvb, zbuf);
  gemm_bt<1><<<dim3(8, 32),  256, 0, stream>>>((const short*)zbuf, mob, bo, d_out, 1024, 1024);
}

// Round 16
// 106.707 us; speedup vs baseline: 1.2225x; 1.2225x over previous
//
#include <hip/hip_runtime.h>
#include <stdint.h>

typedef __attribute__((ext_vector_type(8))) short short8;
typedef __attribute__((ext_vector_type(4))) float f32x4;

#define AS1(p) ((const __attribute__((address_space(1))) void*)(p))
#define AS3(p) ((__attribute__((address_space(3))) void*)(p))

__device__ __forceinline__ void gload_lds16(const void* g, void* l) {
  __builtin_amdgcn_global_load_lds(AS1(g), AS3(l), 16, 0, 0);
}

__device__ __forceinline__ uint32_t cvtpk_bf16(float a, float b) {
  uint32_t d;
  asm("v_cvt_pk_bf16_f32 %0, %1, %2" : "=v"(d) : "v"(a), "v"(b));
  return d;
}

__device__ __forceinline__ float fast_exp2(float x) {
#if __has_builtin(__builtin_amdgcn_exp2f)
  return __builtin_amdgcn_exp2f(x);
#else
  return exp2f(x);
#endif
}

// Q pre-scale: 1/sqrt(64) * log2(e)  (exp2-based softmax)
#define QSCALE 0.1803368801111244f

// ---------------- fused prep: x/wqkv/wo casts + bias concat (one launch) ----------------
__global__ void prep_k(const float* __restrict__ x, const float* __restrict__ wq,
                       const float* __restrict__ wk, const float* __restrict__ wv,
                       const float* __restrict__ wo, const float* __restrict__ bq,
                       const float* __restrict__ bk, const float* __restrict__ bv,
                       uint2* __restrict__ xb, uint2* __restrict__ wqkvb,
                       uint2* __restrict__ mob, float* __restrict__ bqkv) {
  const int bid = blockIdx.x, tid = threadIdx.x;
  if (bid < 4096) {                       // cast x -> bf16
    int i = bid * 256 + tid;
    float4 v = ((const float4*)x)[i];
    uint2 o; o.x = cvtpk_bf16(v.x, v.y); o.y = cvtpk_bf16(v.z, v.w);
    xb[i] = o;
  } else if (bid < 7168) {                // concat+cast W_Q|W_K|W_V (already [n][k])
    int i = (bid - 4096) * 256 + tid;
    int e = i * 4;
    const float* src = (e < (1 << 20)) ? (wq + e)
                     : (e < (2 << 20)) ? (wk + (e - (1 << 20)))
                                       : (wv + (e - (2 << 20)));
    float4 v = *(const float4*)src;
    uint2 o; o.x = cvtpk_bf16(v.x, v.y); o.y = cvtpk_bf16(v.z, v.w);
    wqkvb[i] = o;
  } else if (bid < 8192) {                // gather+cast W_O -> [d][i*64+h]
    int i = (bid - 7168) * 256 + tid;
    int o4 = i * 4;
    int d = o4 >> 10, c = o4 & 1023;
    const float* s = wo + ((c >> 6) << 16) + (d << 6) + (c & 63);
    float4 v = *(const float4*)s;
    uint2 o; o.x = cvtpk_bf16(v.x, v.y); o.y = cvtpk_bf16(v.z, v.w);
    mob[i] = o;
  } else {                                // bias concat (fp32)
    int i = (bid - 8192) * 256 + tid;
    bqkv[i] = (i < 1024) ? bq[i] : (i < 2048) ? bk[i - 1024] : bv[i - 2048];
  }
}

// ---------------- GEMM1: C[M,N] = A[M,K] * B^T + bias (128x128 tile, R10-proven) ----------------
// BK=64 + T2 XOR-swizzle: 16B chunk c8 of row r stored at c8^(r&7) via
// pre-swizzled global source; ds_read at (kk*4+g)^(q&7). bf16 out, q pre-scaled.
__global__ __launch_bounds__(256) void gemm_bt(const short* __restrict__ A,
                                               const short* __restrict__ Bm,
                                               const float* __restrict__ bias,
                                               unsigned short* __restrict__ Cout,
                                               int K, int ldc) {
  __shared__ short As[128 * 64];
  __shared__ short Bs[128 * 64];
  const int t = threadIdx.x;
  const int l = t & 63, w = t >> 6;
  const int wr = w >> 1, wc = w & 1;
  const int q = l & 15, g = l >> 4;
  const long brow = (long)blockIdx.y * 128;
  const long bcol = (long)blockIdx.x * 128;
  f32x4 acc[4][4] = {};
  const int r8 = t >> 3;                  // row within 32-row group
  const int sc8 = (t & 7) ^ (r8 & 7);     // pre-swizzled global column chunk
  const short* aptr = A + (brow + r8) * (long)K + sc8 * 8;
  const short* bptr = Bm + (bcol + r8) * (long)K + sc8 * 8;
  const int qs = q & 7;                   // read-side swizzle key
  for (int k0 = 0; k0 < K; k0 += 64) {
#pragma unroll
    for (int c = 0; c < 4; ++c) {
      gload_lds16(aptr + k0 + c * 32 * (long)K, &As[(c * 256 + t) * 8]);
      gload_lds16(bptr + k0 + c * 32 * (long)K, &Bs[(c * 256 + t) * 8]);
    }
    __syncthreads();
    short8 af[4][2], bfr[4][2];
#pragma unroll
    for (int m = 0; m < 4; ++m)
#pragma unroll
      for (int kk = 0; kk < 2; ++kk)
        af[m][kk] = *(const short8*)&As[(wr * 64 + m * 16 + q) * 64 + ((kk * 4 + g) ^ qs) * 8];
#pragma unroll
    for (int n = 0; n < 4; ++n)
#pragma unroll
      for (int kk = 0; kk < 2; ++kk)
        bfr[n][kk] = *(const short8*)&Bs[(wc * 64 + n * 16 + q) * 64 + ((kk * 4 + g) ^ qs) * 8];
#pragma unroll
    for (int m = 0; m < 4; ++m)
#pragma unroll
      for (int n = 0; n < 4; ++n) {
        acc[m][n] = __builtin_amdgcn_mfma_f32_16x16x32_bf16(af[m][0], bfr[n][0], acc[m][n], 0, 0, 0);
        acc[m][n] = __builtin_amdgcn_mfma_f32_16x16x32_bf16(af[m][1], bfr[n][1], acc[m][n], 0, 0, 0);
      }
    if (k0 + 64 < K) __syncthreads();     // readers done before next stage overwrites
  }
#pragma unroll
  for (int m = 0; m < 4; ++m)
#pragma unroll
    for (int n = 0; n < 4; ++n)
#pragma unroll
      for (int r = 0; r < 4; ++r) {
        long row = brow + wr * 64 + m * 16 + g * 4 + r;
        long col = bcol + wc * 64 + n * 16 + q;
        float v = acc[m][n][r] + bias[col];
        if (col < 1024) v *= QSCALE;
        Cout[row * ldc + col] = (unsigned short)cvtpk_bf16(v, v);
      }
}

// ---------------- GEMM2: out-proj, 128x64 tile for 2 blocks/CU (was 1) ----------------
// Same proven staging/swizzle/fragment patterns; 4 waves each own 32 rows x
// 64 cols (acc[2][4]); B-tile is 64 rows = 2 of the proven 32-row staging
// passes. fp32 out + bias. Grid dim3(N/64=16, M/128=32) = 512 blocks.
__global__ __launch_bounds__(256) void gemm_bt2(const short* __restrict__ A,
                                                const short* __restrict__ Bm,
                                                const float* __restrict__ bias,
                                                float* __restrict__ Cout,
                                                int K, int ldc) {
  __shared__ short As[128 * 64];
  __shared__ short Bs[64 * 64];
  const int t = threadIdx.x;
  const int l = t & 63, w = t >> 6;       // wave w owns rows w*32..w*32+31
  const int q = l & 15, g = l >> 4;
  const long brow = (long)blockIdx.y * 128;
  const long bcol = (long)blockIdx.x * 64;
  f32x4 acc[2][4] = {};
  const int r8 = t >> 3;                  // row within 32-row group
  const int sc8 = (t & 7) ^ (r8 & 7);     // pre-swizzled global column chunk
  const short* aptr = A + (brow + r8) * (long)K + sc8 * 8;
  const short* bptr = Bm + (bcol + r8) * (long)K + sc8 * 8;
  const int qs = q & 7;                   // read-side swizzle key
  for (int k0 = 0; k0 < K; k0 += 64) {
#pragma unroll
    for (int c = 0; c < 4; ++c)
      gload_lds16(aptr + k0 + c * 32 * (long)K, &As[(c * 256 + t) * 8]);
#pragma unroll
    for (int c = 0; c < 2; ++c)
      gload_lds16(bptr + k0 + c * 32 * (long)K, &Bs[(c * 256 + t) * 8]);
    __syncthreads();
    short8 af[2][2], bfr[4][2];
#pragma unroll
    for (int m = 0; m < 2; ++m)
#pragma unroll
      for (int kk = 0; kk < 2; ++kk)
        af[m][kk] = *(const short8*)&As[(w * 32 + m * 16 + q) * 64 + ((kk * 4 + g) ^ qs) * 8];
#pragma unroll
    for (int n = 0; n < 4; ++n)
#pragma unroll
      for (int kk = 0; kk < 2; ++kk)
        bfr[n][kk] = *(const short8*)&Bs[(n * 16 + q) * 64 + ((kk * 4 + g) ^ qs) * 8];
#pragma unroll
    for (int m = 0; m < 2; ++m)
#pragma unroll
      for (int n = 0; n < 4; ++n) {
        acc[m][n] = __builtin_amdgcn_mfma_f32_16x16x32_bf16(af[m][0], bfr[n][0], acc[m][n], 0, 0, 0);
        acc[m][n] = __builtin_amdgcn_mfma_f32_16x16x32_bf16(af[m][1], bfr[n][1], acc[m][n], 0, 0, 0);
      }
    if (k0 + 64 < K) __syncthreads();
  }
#pragma unroll
  for (int m = 0; m < 2; ++m)
#pragma unroll
    for (int n = 0; n < 4; ++n)
#pragma unroll
      for (int r = 0; r < 4; ++r) {
        long row = brow + w * 32 + m * 16 + g * 4 + r;
        long col = bcol + n * 16 + q;
        Cout[row * ldc + col] = acc[m][n][r] + bias[col];
      }
}

// ---------------- flash attention (paired q-tiles SHARING staged KV tiles) ----------------
// R12-exact (proven 52.6us, absmax 0.0078). 512 blocks x 256 threads (4 waves).
// Block = (head bh, pair pr): q-tiles qtA=31-pr, qtB=pr. ONE pass over KV
// tiles 0..qtA; each staged tile feeds A always and B when j<=qtB. Blocks c
// and c+256 share a CU and pr(c)+pr(c+256)=15 -> per-CU step count constant.
__global__ __launch_bounds__(256) void attn(const short* __restrict__ qkv,
                                            unsigned short* __restrict__ zb) {
  __shared__ short Ks[2][64 * 64];
  __shared__ short Vt[64 * 64];
  __shared__ unsigned short Ps[8][16 * 64];
  const int bid = blockIdx.x;
  const int r_ = bid >> 7;                 // 0..3
  const int u_ = (bid >> 3) & 15;          // 0..15
  const int x_ = bid & 7;                  // XCD slot (4 heads per slot -> L2 reuse)
  const int bh = r_ * 8 + x_;              // head 0..31
  const int pr = (r_ < 2) ? u_ : 15 - u_;  // work-balancing: pr(c)+pr(c+256)=15
  const int qtA = 31 - pr, qtB = pr;
  const int b = bh >> 4, h = bh & 15;
  const int t = threadIdx.x, l = t & 63, w = t >> 6;
  const int lq = l & 15, g = l >> 4;
  const int u = t >> 3, c8 = t & 7;        // staging coords
  const long rowbase = (long)b * 2048;
  const short* qp = qkv + rowbase * 3072 + h * 64;
  const short* kp = qp + 1024;
  const short* vp = qp + 2048;

  short8 qfA[2], qfB[2];
#pragma unroll
  for (int kg = 0; kg < 2; ++kg) {
    qfA[kg] = *(const short8*)(qp + (long)(qtA * 64 + w * 16 + lq) * 3072 + kg * 32 + g * 8);
    qfB[kg] = *(const short8*)(qp + (long)(qtB * 64 + w * 16 + lq) * 3072 + kg * 32 + g * 8);
  }
  f32x4 zA[4] = {}, zB[4] = {};
  float mA = -1e30f, lA = 0.0f, mB = -1e30f, lB = 0.0f;

  // one attention step over the staged KV tile (ksb = K buffer, Vt shared)
  auto step = [&](const short* ksb, unsigned short* Pw, f32x4 (&zacc)[4],
                  float& mrun, float& lrun, short8 (&qf)[2], bool diag) {
    f32x4 sacc[4] = {};
#pragma unroll
    for (int m = 0; m < 4; ++m) {
#pragma unroll
      for (int kg = 0; kg < 2; ++kg) {
        int krow = m * 16 + lq;
        int blk = kg * 4 + g;
        short8 kf = *(const short8*)&ksb[krow * 64 + (blk ^ (krow & 7)) * 8];
        sacc[m] = __builtin_amdgcn_mfma_f32_16x16x32_bf16(kf, qf[kg], sacc[m], 0, 0, 0);
      }
    }
    if (diag) {
#pragma unroll
      for (int m = 0; m < 4; ++m)
#pragma unroll
        for (int r = 0; r < 4; ++r)
          if (m * 16 + g * 4 + r > w * 16 + lq) sacc[m][r] = -1e30f;
    }
    // tree max (depth 4)
    float red[8];
#pragma unroll
    for (int i2 = 0; i2 < 8; ++i2)
      red[i2] = fmaxf(sacc[i2 >> 2][i2 & 3], sacc[2 + (i2 >> 2)][i2 & 3]);
#pragma unroll
    for (int i2 = 0; i2 < 4; ++i2) red[i2] = fmaxf(red[i2], red[i2 + 4]);
    float mx = fmaxf(fmaxf(red[0], red[2]), fmaxf(red[1], red[3]));
    mx = fmaxf(mx, __shfl_xor(mx, 16));
    mx = fmaxf(mx, __shfl_xor(mx, 32));
    // defer-max: rescale only when tile max overflows the 2^8 headroom
    if (!__all(mx <= mrun + 8.0f)) {
      float mnew = fmaxf(mrun, mx);
      float alpha = fast_exp2(mrun - mnew);
      lrun *= alpha;
#pragma unroll
      for (int r = 0; r < 4; ++r) {
        float ar = __shfl(alpha, g * 4 + r);
#pragma unroll
        for (int n2 = 0; n2 < 4; ++n2) zacc[n2][r] *= ar;
      }
      mrun = mnew;
    }
#pragma unroll
    for (int m = 0; m < 4; ++m)
#pragma unroll
      for (int r = 0; r < 4; ++r) sacc[m][r] = fast_exp2(sacc[m][r] - mrun);
    // tree sum (depth 4)
    float rs[8];
#pragma unroll
    for (int i2 = 0; i2 < 8; ++i2)
      rs[i2] = sacc[i2 >> 2][i2 & 3] + sacc[2 + (i2 >> 2)][i2 & 3];
#pragma unroll
    for (int i2 = 0; i2 < 4; ++i2) rs[i2] = rs[i2] + rs[i2 + 4];
    float ts = (rs[0] + rs[2]) + (rs[1] + rs[3]);
    ts += __shfl_xor(ts, 16);
    ts += __shfl_xor(ts, 32);
    lrun += ts;
    // pack P (cvt_pk) -> per-step LDS region (XOR-swizzled by q)
#pragma unroll
    for (int m = 0; m < 4; ++m) {
      uint2 wv;
      wv.x = cvtpk_bf16(sacc[m][0], sacc[m][1]);
      wv.y = cvtpk_bf16(sacc[m][2], sacc[m][3]);
      int c = m * 4 + g;
      int csw = c ^ ((lq & 7) << 1);
      *(uint2*)&Pw[lq * 64 + csw * 4] = wv;
    }
    short8 pf[2];
#pragma unroll
    for (int kg2 = 0; kg2 < 2; ++kg2) {
      int c0 = kg2 * 8 + g * 2;
      int c0s = c0 ^ ((lq & 7) << 1);
      pf[kg2] = *(const short8*)&Pw[lq * 64 + c0s * 4];
    }
#pragma unroll
    for (int n2 = 0; n2 < 4; ++n2) {
#pragma unroll
      for (int kg2 = 0; kg2 < 2; ++kg2) {
        int dh = n2 * 16 + lq;
        int sw = (dh & 7) ^ ((dh >> 3) & 7);
        int blk = kg2 * 4 + g;
        short8 vf = *(const short8*)&Vt[dh * 64 + ((blk ^ sw) * 8)];
        zacc[n2] = __builtin_amdgcn_mfma_f32_16x16x32_bf16(pf[kg2], vf, zacc[n2], 0, 0, 0);
      }
    }
  };

  auto stageK = [&](int tile, int buf) {
#pragma unroll
    for (int i = 0; i < 2; ++i) {
      int r = i * 32 + u;
      int cbk = (c8 ^ (r & 7)) * 8;
      gload_lds16(kp + (long)(tile * 64 + r) * 3072 + cbk, &Ks[buf][i * 2048 + t * 8]);
    }
  };

  // prologue: issue staging for kv tile 0 into buffer 0
  short8 va0, va1;
  {
    stageK(0, 0);
    const short* vrow = vp + (long)(2 * u) * 3072 + c8 * 8;
    va0 = *(const short8*)vrow;
    va1 = *(const short8*)(vrow + 3072);
  }

  for (int j = 0; j <= qtA; ++j) {
    const int buf = j & 1;
    asm volatile("s_waitcnt vmcnt(0)" ::: "memory");
    __builtin_amdgcn_sched_barrier(0);
    __builtin_amdgcn_s_barrier();   // K(j) in LDS; prev step's Vt/Ks readers done
    // write V regs -> Vt (single buffer; prev readers completed before barrier)
    {
      int blk = u >> 2, rl = (u & 3) * 2;
#pragma unroll
      for (int idx = 0; idx < 8; ++idx) {
        int dh = c8 * 8 + idx;
        int sw = (dh & 7) ^ ((dh >> 3) & 7);
        uint32_t pk = (uint32_t)(uint16_t)va0[idx] | ((uint32_t)(uint16_t)va1[idx] << 16);
        *(uint32_t*)&Vt[dh * 64 + ((blk ^ sw) * 8) + rl] = pk;
      }
    }
    if (j < qtA) {
      // prefetch next KV tile (hidden under this step's compute)
      stageK(j + 1, buf ^ 1);
      const short* vrow = vp + (long)((j + 1) * 64 + 2 * u) * 3072 + c8 * 8;
      va0 = *(const short8*)vrow;
      va1 = *(const short8*)(vrow + 3072);
    }
    asm volatile("s_waitcnt lgkmcnt(0)" ::: "memory");  // Vt writes visible
    __builtin_amdgcn_sched_barrier(0);
    __builtin_amdgcn_s_barrier();
    // apply tile j to q-tile A (always) and B (while in range) — independent chains
    step(&Ks[buf][0], &Ps[w][0], zA, mA, lA, qfA, j == qtA);
    if (j <= qtB)
      step(&Ks[buf][0], &Ps[4 + w][0], zB, mB, lB, qfB, j == qtB);
  }

  auto wout = [&](f32x4 (&zacc)[4], float lrun, int qt) {
#pragma unroll
    for (int r = 0; r < 4; ++r) {
      float linv = 1.0f / __shfl(lrun, g * 4 + r);
      long grow = rowbase + qt * 64 + w * 16 + g * 4 + r;
#pragma unroll
      for (int n2 = 0; n2 < 4; ++n2) {
        int col = h * 64 + n2 * 16 + lq;
        float zv = zacc[n2][r] * linv;
        zb[grow * 1024 + col] = (unsigned short)cvtpk_bf16(zv, zv);
      }
    }
  };
  wout(zA, lA, qtA);
  wout(zB, lB, qtB);
}

extern "C" void kernel_launch(void* const* d_in, const int* in_sizes, int n_in,
                              void* d_out, int out_size, void* d_ws, size_t ws_size,
                              hipStream_t stream) {
  const float* x  = (const float*)d_in[0];
  const float* wq = (const float*)d_in[1];
  const float* wk = (const float*)d_in[2];
  const float* wv = (const float*)d_in[3];
  const float* wo = (const float*)d_in[4];
  const float* bq = (const float*)d_in[5];
  const float* bk = (const float*)d_in[6];
  const float* bv = (const float*)d_in[7];
  const float* bo = (const float*)d_in[8];
  char* ws = (char*)d_ws;
  if (ws_size < ((size_t)48 * 1024 * 1024 + 16384)) return;  // need ~48MB
  short*          xb    = (short*)(ws);                         //  8 MB
  short*          qkvb  = (short*)(ws + ((size_t)8  << 20));    // 24 MB
  unsigned short* zbuf  = (unsigned short*)(ws + ((size_t)32 << 20)); // 8 MB
  short*          wqkvb = (short*)(ws + ((size_t)40 << 20));    //  6 MB
  short*          mob   = (short*)(ws + ((size_t)46 << 20));    //  2 MB
  float*          bqkv  = (float*)(ws + ((size_t)48 << 20));    // 12 KB

  prep_k<<<8204, 256, 0, stream>>>(x, wq, wk, wv, wo, bq, bk, bv,
                                   (uint2*)xb, (uint2*)wqkvb, (uint2*)mob, bqkv);
  gemm_bt <<<dim3(24, 32), 256, 0, stream>>>(xb, wqkvb, bqkv, (unsigned short*)qkvb, 1024, 3072);
  attn    <<<512,          256, 0, stream>>>(qkvb, zbuf);
  gemm_bt2<<<dim3(16, 32), 256, 0, stream>>>((const short*)zbuf, mob, bo, (float*)d_out, 1024, 1024);
}